// Round 15
// baseline (119.401 us; speedup 1.0000x reference)
//
#include <hip/hip_runtime.h>
#include <hip/hip_bf16.h>

typedef __bf16 bf16x8 __attribute__((ext_vector_type(8)));
typedef float f32x4 __attribute__((ext_vector_type(4)));

#define LAMBDA_INIT 0.3555090675909693f
#define CEXP 0.18033688011112042f   // 0.125 * log2(e), folded into Q at projection

// ws layout (bytes):
//  q    : [0, 4.19M)       bf16 [16384][128] row-major, PRE-SCALED by CEXP
//  kimg : [4.19M, 8.39M)   bf16 [4][64][2][8 regions][64 slots][8]  (frag image)
//  vimg : [8.39M, 12.58M)  bf16 [4][64][16 regions][64 slots][8]    (frag image)
//  part : [12.58M, +34.1M) recs x 16640B (l[64] f32 + O[64][128] bf16)
//  WT   : after part       bf16 [3][128][1024]
#define K_OFF   ((size_t)16384 * 128)
#define VT_OFF  ((size_t)2 * 16384 * 128)
#define PART_OFF_BYTES ((size_t)12582912)
#define REC_FLOATS 4160  // 64 l + 4096 words of bf16 O

__device__ __forceinline__ unsigned short f2bf(float f) {
    __hip_bfloat16 h = __float2bfloat16(f);
    unsigned short u;
    __builtin_memcpy(&u, &h, 2);
    return u;
}
__device__ __forceinline__ float bf2f(unsigned short u) {
    unsigned int x = ((unsigned int)u) << 16;
    float f;
    __builtin_memcpy(&f, &x, 4);
    return f;
}
__device__ __forceinline__ unsigned int cvt_pk_bf16(float a, float b) {
    unsigned int r;
    asm volatile("v_cvt_pk_bf16_f32 %0, %1, %2" : "=v"(r) : "v"(a), "v"(b));
    return r;
}

// ---------------- W pre-transpose: [1024][128] f32 -> [128][1024] bf16 ----------------
__global__ __launch_bounds__(256) void prep_wt(
    const float* __restrict__ Wq, const float* __restrict__ Wk,
    const float* __restrict__ Wv, unsigned short* __restrict__ WT) {
    const int kt = blockIdx.x, nt = blockIdx.y, mat = blockIdx.z;
    const float* W = (mat == 0) ? Wq : (mat == 1) ? Wk : Wv;
    unsigned short* O = WT + (size_t)mat * 128 * 1024;
    __shared__ float tb[64][65];
    const int r = threadIdx.x >> 2, c4 = (threadIdx.x & 3) * 16;
    for (int j = 0; j < 4; ++j) {
        float4 v = *(const float4*)&W[(size_t)(kt * 64 + r) * 128 + nt * 64 + c4 + j * 4];
        tb[r][c4 + j * 4 + 0] = v.x;
        tb[r][c4 + j * 4 + 1] = v.y;
        tb[r][c4 + j * 4 + 2] = v.z;
        tb[r][c4 + j * 4 + 3] = v.w;
    }
    __syncthreads();
    unsigned short tmp[16];
    for (int j = 0; j < 16; ++j) tmp[j] = f2bf(tb[c4 + j][r]);
    *(uint4*)&O[(size_t)(nt * 64 + r) * 1024 + kt * 64 + c4] = *(uint4*)&tmp[0];
    *(uint4*)&O[(size_t)(nt * 64 + r) * 1024 + kt * 64 + c4 + 8] = *(uint4*)&tmp[8];
}

// ---------------- QKV projection, 64-row tiles ----------------
// grid (256, 3): 768 blocks = exactly 3/CU, all co-resident -> zero makespan
// imbalance (the (128,3) grid left half the CUs with 2 serial blocks).
// id = rx + 256*mat: same row-tile across mats lands on the SAME XCD (256%8==0).
// Q epilogue pre-scales by CEXP (softmax scale folded in; MOFF normalization
// cancels in o/lsum). K/V epilogues write the attention frag images.
__global__ __launch_bounds__(256) void qkv_gemm(
    const float* __restrict__ x, const unsigned short* __restrict__ WT,
    unsigned short* __restrict__ qkv) {
    const int tid = threadIdx.x;
    const int l = tid & 63, w = tid >> 6;
    const int g = l >> 4, i16 = l & 15;
    const int row0 = blockIdx.x * 64;
    const int mat = blockIdx.y;
    const unsigned short* Wt = WT + (size_t)mat * 128 * 1024;

    __shared__ unsigned short xs[64][72];
    __shared__ unsigned short wt[128][72];

    f32x4 acc[8];
    const f32x4 z4 = {0.f, 0.f, 0.f, 0.f};
    for (int nb = 0; nb < 8; ++nb) acc[nb] = z4;

    for (int k0 = 0; k0 < 1024; k0 += 64) {
        __syncthreads();
        {   // stage x tile (64 x 64) f32 -> bf16
            const int c = (tid & 15) * 4;
            const int rb = tid >> 4;
            #pragma unroll
            for (int it = 0; it < 4; ++it) {
                int r = (rb + it * 16) & 63;
                const float4 v = *(const float4*)&x[(size_t)(row0 + r) * 1024 + k0 + c];
                ushort4 pk = make_ushort4(f2bf(v.x), f2bf(v.y), f2bf(v.z), f2bf(v.w));
                *(ushort4*)&xs[r][c] = pk;
            }
        }
        {   // stage W^T tile (128 n x 64 k) bf16 vectorized
            #pragma unroll
            for (int it = 0; it < 4; ++it) {
                int lin = it * 256 + tid;
                int n = lin >> 3, k8 = (lin & 7) * 8;
                *(uint4*)&wt[n][k8] = *(const uint4*)&Wt[(size_t)n * 1024 + k0 + k8];
            }
        }
        __syncthreads();

        bf16x8 af0 = *(const bf16x8*)&xs[w * 16 + i16][8 * g];
        bf16x8 af1 = *(const bf16x8*)&xs[w * 16 + i16][32 + 8 * g];
        #pragma unroll
        for (int nb = 0; nb < 8; ++nb) {
            bf16x8 b0 = *(const bf16x8*)&wt[nb * 16 + i16][8 * g];
            bf16x8 b1 = *(const bf16x8*)&wt[nb * 16 + i16][32 + 8 * g];
            acc[nb] = __builtin_amdgcn_mfma_f32_16x16x32_bf16(af0, b0, acc[nb], 0, 0, 0);
            acc[nb] = __builtin_amdgcn_mfma_f32_16x16x32_bf16(af1, b1, acc[nb], 0, 0, 0);
        }
    }

    // epilogue: bounce through LDS (alias over wt), then frag-image writes
    __syncthreads();
    unsigned short(*ts)[136] = (unsigned short(*)[136]) & wt[0][0];
    const float qscale = (mat == 0) ? CEXP : 1.0f;
    for (int nb = 0; nb < 8; ++nb)
        for (int r = 0; r < 4; ++r)
            ts[w * 16 + g * 4 + r][nb * 16 + i16] = f2bf(acc[nb][r] * qscale);
    __syncthreads();

    const int bq = row0 >> 12;           // batch
    const int s = (row0 >> 6) & 63;      // kv-tile index
    if (mat == 0) {
        unsigned short* outp = qkv + (size_t)row0 * 128;
        #pragma unroll
        for (int it = 0; it < 4; ++it) {
            int tr = it * 16 + (tid >> 4), dv0 = (tid & 15) * 8;
            *(uint4*)&outp[tr * 128 + dv0] = *(const uint4*)&ts[tr][dv0];
        }
    } else if (mat == 1) {
        // K frag image: [(b*64+s)*2+branch][region=cb*2+cc][slot=gq*16+i16][8]
        unsigned short* kimg = qkv + K_OFF + ((size_t)(bq * 64 + s) * 2) * 4096;
        #pragma unroll
        for (int it = 0; it < 4; ++it) {
            int lin = it * 256 + tid;      // 0..1023
            int branch_ = (lin >> 9) & 1;
            int region = (lin >> 6) & 7;
            int slot = lin & 63;
            int row = (region >> 1) * 16 + (slot & 15);
            int d = branch_ * 64 + (region & 1) * 32 + (slot >> 4) * 8;
            uint4 vv = *(const uint4*)&ts[row][d];
            *(uint4*)&kimg[(size_t)branch_ * 4096 + (region * 64 + slot) * 8] = vv;
        }
    } else {
        // V frag image: [b*64+s][region=nb*2+cc][slot=gq*16+i16][8]
        unsigned short* vimg = qkv + VT_OFF + (size_t)(bq * 64 + s) * 8192;
        #pragma unroll
        for (int it = 0; it < 4; ++it) {
            int lin = it * 256 + tid;      // 0..1023
            int region = lin >> 6;         // 0..15
            int slot = lin & 63;
            int dv = (region >> 1) * 16 + (slot & 15);
            int kv0 = (region & 1) * 32 + (slot >> 4) * 8;
            unsigned short tmp[8];
            #pragma unroll
            for (int e = 0; e < 8; ++e) tmp[e] = ts[kv0 + e][dv];
            *(uint4*)&vimg[(region * 64 + slot) * 8] = *(uint4*)tmp;
        }
    }
}

// ---------------- Differential causal flash attention, paired rows ----------------
// grid (32, 4, nc*2): z = c*2+branch, nc = 4. Block owns adjacent row PAIR
// (t_e = 62-2bxe, t_o = 63-2bxe); every staged kv-tile serves two 64-row
// q-tiles. COMPLEMENT SWIZZLE: bxe = (c&1)?31-bx:bx -> same-CU blocks get
// complementary durations -> every CU gets equal tile totals.
// Q pre-scaled by CEXP and fixed-max offset folded out: p = exp2(S').
// Wave w: q-rows [w*16,w*16+16) of BOTH rows for QK/softmax; PV computes ALL
// q x dv-slice [32w,32w+32) with V in REGISTERS (direct frag-image loads).
// P via 16KB psf (cross-wave -> barrier before PV). LDS = 24KB.
// Empty chunks return WITHOUT writing; combine skips them.
__global__ __launch_bounds__(256, 3) void diff_attn_pair(
    const unsigned short* __restrict__ q, const unsigned short* __restrict__ kimg,
    const unsigned short* __restrict__ vimg,
    float* __restrict__ part, int ncs) {
    const int bx = blockIdx.x, b = blockIdx.y;
    const int c = blockIdx.z >> 1, branch = blockIdx.z & 1;
    const int bxe = (c & 1) ? (31 - bx) : bx;   // complement swizzle (load balance)
    const int t_o = 63 - 2 * bxe, t_e = t_o - 1;
    const int n = t_o + 1;
    const int s_lo = (c * n) >> ncs, smax = ((c + 1) * n) >> ncs;

    if (s_lo >= smax) return;  // empty chunk: no record (combine skips)

    const int tid = threadIdx.x;
    const int l = tid & 63, w = tid >> 6;
    const int gq = l >> 4, i16 = l & 15;
    const float NEGINF = -__builtin_inff();

    __shared__ unsigned short ksf[4096];  //  8 KB: [8 region][64 slot][8]
    __shared__ unsigned short psf[8192];  // 16 KB: [2 qset][4 qg][2 cc][64 slot][8]

    float* recA = part + ((((size_t)(b * 64 + t_e) << ncs) + c) * 2 + branch) * REC_FLOATS;
    float* recB = part + ((((size_t)(b * 64 + t_o) << ncs) + c) * 2 + branch) * REC_FLOATS;
    const bool emptyA = (s_lo > t_e);  // chunk == {t_o}: no A record

    const size_t bbase = (size_t)b * 4096;
    const unsigned short* kimg_b = kimg + (size_t)b * 524288;
    const unsigned short* vimg_b = vimg + (size_t)b * 524288;
    const int tid8 = tid * 8;
    const int l8 = l * 8;
    const f32x4 z4 = {0.f, 0.f, 0.f, 0.f};

    bf16x8 qfA[2], qfB[2];
    #pragma unroll
    for (int cc = 0; cc < 2; ++cc) {
        qfA[cc] = *(const bf16x8*)&q[(bbase + t_e * 64 + w * 16 + i16) * 128 + branch * 64 + cc * 32 + 8 * gq];
        qfB[cc] = *(const bf16x8*)&q[(bbase + t_o * 64 + w * 16 + i16) * 128 + branch * 64 + cc * 32 + 8 * gq];
    }

    float lsumA = 0.f, lsumB = 0.f;
    f32x4 acc[2][4][2];  // [qset][qg][j]  (dv slice w*32 + j*16)
    for (int qs = 0; qs < 2; ++qs)
        for (int qg = 0; qg < 4; ++qg)
            for (int j = 0; j < 2; ++j) acc[qs][qg][j] = z4;

    // P write slots (per cb, shared formula for both qsets; +qset*8 regions)
    int pdst[4];
    #pragma unroll
    for (int cb = 0; cb < 4; ++cb)
        pdst[cb] = ((w * 2 + (cb >> 1)) * 64 + ((cb & 1) * 2 + (gq >> 1)) * 16 + i16) * 8 + (gq & 1) * 4;

    uint4 kr0, kr1;
    bf16x8 vb00, vb01, vb10, vb11;  // V dv-slice frags, [j][cc]

#define K_ISSUE(s_) do {                                                            \
        const unsigned short* kp = &kimg_b[((size_t)(s_) * 2 + branch) * 4096];     \
        kr0 = *(const uint4*)&kp[tid8];                                             \
        kr1 = *(const uint4*)&kp[tid8 + 2048];                                      \
    } while (0)
#define V_ISSUE(s_) do {                                                            \
        const unsigned short* vp = &vimg_b[(size_t)(s_) * 8192 + w * 2048];         \
        vb00 = *(const bf16x8*)&vp[l8];                                             \
        vb01 = *(const bf16x8*)&vp[512 + l8];                                       \
        vb10 = *(const bf16x8*)&vp[1024 + l8];                                      \
        vb11 = *(const bf16x8*)&vp[1536 + l8];                                      \
    } while (0)

    K_ISSUE(s_lo);
    V_ISSUE(s_lo);
    #pragma unroll 1
    for (int s = s_lo; s < smax; ++s) {
        __syncthreads();                              // B1: prev PV done with ksf/psf
        *(uint4*)&ksf[tid8] = kr0;
        *(uint4*)&ksf[tid8 + 2048] = kr1;
        if (s + 1 < smax) K_ISSUE(s + 1);
        __syncthreads();                              // B2: ksf ready
        const bool aAct = (s != t_o);

        // ---- qset A (row t_e) ----
        if (aAct) {
            f32x4 sc[4];
            for (int cb = 0; cb < 4; ++cb) sc[cb] = z4;
            __builtin_amdgcn_s_setprio(1);
            #pragma unroll
            for (int cb = 0; cb < 4; ++cb)
                for (int cc = 0; cc < 2; ++cc) {
                    bf16x8 kf = *(const bf16x8*)&ksf[((cb * 2 + cc) * 64 + l) * 8];
                    sc[cb] = __builtin_amdgcn_mfma_f32_16x16x32_bf16(kf, qfA[cc], sc[cb], 0, 0, 0);
                }
            __builtin_amdgcn_s_setprio(0);
            if (s == t_e) {
                int ql = w * 16 + i16;
                for (int cb = 0; cb < 4; ++cb)
                    for (int r = 0; r < 4; ++r)
                        if (cb * 16 + gq * 4 + r > ql) sc[cb][r] = NEGINF;
            }
            #pragma unroll
            for (int cb = 0; cb < 4; ++cb) {
                float p0 = exp2f(sc[cb][0]);
                float p1 = exp2f(sc[cb][1]);
                float p2 = exp2f(sc[cb][2]);
                float p3 = exp2f(sc[cb][3]);
                lsumA += (p0 + p1) + (p2 + p3);
                uint2 pw;
                pw.x = cvt_pk_bf16(p0, p1);
                pw.y = cvt_pk_bf16(p2, p3);
                *(uint2*)&psf[pdst[cb]] = pw;
            }
        }
        // ---- qset B (row t_o) ----
        {
            f32x4 sc[4];
            for (int cb = 0; cb < 4; ++cb) sc[cb] = z4;
            __builtin_amdgcn_s_setprio(1);
            #pragma unroll
            for (int cb = 0; cb < 4; ++cb)
                for (int cc = 0; cc < 2; ++cc) {
                    bf16x8 kf = *(const bf16x8*)&ksf[((cb * 2 + cc) * 64 + l) * 8];
                    sc[cb] = __builtin_amdgcn_mfma_f32_16x16x32_bf16(kf, qfB[cc], sc[cb], 0, 0, 0);
                }
            __builtin_amdgcn_s_setprio(0);
            if (s == t_o) {
                int ql = w * 16 + i16;
                for (int cb = 0; cb < 4; ++cb)
                    for (int r = 0; r < 4; ++r)
                        if (cb * 16 + gq * 4 + r > ql) sc[cb][r] = NEGINF;
            }
            #pragma unroll
            for (int cb = 0; cb < 4; ++cb) {
                float p0 = exp2f(sc[cb][0]);
                float p1 = exp2f(sc[cb][1]);
                float p2 = exp2f(sc[cb][2]);
                float p3 = exp2f(sc[cb][3]);
                lsumB += (p0 + p1) + (p2 + p3);
                uint2 pw;
                pw.x = cvt_pk_bf16(p0, p1);
                pw.y = cvt_pk_bf16(p2, p3);
                *(uint2*)&psf[4096 + pdst[cb]] = pw;
            }
        }
        __syncthreads();                              // B3: psf complete (cross-wave)

        // ---- PV: all q x dv-slice [w*32, w*32+32), V in registers ----
        __builtin_amdgcn_s_setprio(1);
        if (aAct) {
            #pragma unroll
            for (int qg = 0; qg < 4; ++qg) {
                bf16x8 pa0 = *(const bf16x8*)&psf[(qg * 2 + 0) * 512 + l8];
                bf16x8 pa1 = *(const bf16x8*)&psf[(qg * 2 + 1) * 512 + l8];
                acc[0][qg][0] = __builtin_amdgcn_mfma_f32_16x16x32_bf16(pa0, vb00, acc[0][qg][0], 0, 0, 0);
                acc[0][qg][0] = __builtin_amdgcn_mfma_f32_16x16x32_bf16(pa1, vb01, acc[0][qg][0], 0, 0, 0);
                acc[0][qg][1] = __builtin_amdgcn_mfma_f32_16x16x32_bf16(pa0, vb10, acc[0][qg][1], 0, 0, 0);
                acc[0][qg][1] = __builtin_amdgcn_mfma_f32_16x16x32_bf16(pa1, vb11, acc[0][qg][1], 0, 0, 0);
            }
        }
        #pragma unroll
        for (int qg = 0; qg < 4; ++qg) {
            bf16x8 pa0 = *(const bf16x8*)&psf[4096 + (qg * 2 + 0) * 512 + l8];
            bf16x8 pa1 = *(const bf16x8*)&psf[4096 + (qg * 2 + 1) * 512 + l8];
            acc[1][qg][0] = __builtin_amdgcn_mfma_f32_16x16x32_bf16(pa0, vb00, acc[1][qg][0], 0, 0, 0);
            acc[1][qg][0] = __builtin_amdgcn_mfma_f32_16x16x32_bf16(pa1, vb01, acc[1][qg][0], 0, 0, 0);
            acc[1][qg][1] = __builtin_amdgcn_mfma_f32_16x16x32_bf16(pa0, vb10, acc[1][qg][1], 0, 0, 0);
            acc[1][qg][1] = __builtin_amdgcn_mfma_f32_16x16x32_bf16(pa1, vb11, acc[1][qg][1], 0, 0, 0);
        }
        __builtin_amdgcn_s_setprio(0);
        if (s + 1 < smax) V_ISSUE(s + 1);             // fly through next QK/softmax
    }
#undef K_ISSUE
#undef V_ISSUE

    // flush: lsum reduce across gq groups; O slices to both records
    lsumA += __shfl_xor(lsumA, 16);
    lsumA += __shfl_xor(lsumA, 32);
    lsumB += __shfl_xor(lsumB, 16);
    lsumB += __shfl_xor(lsumB, 32);
    if (!emptyA) {
        if (gq == 0) recA[w * 16 + i16] = lsumA;
        unsigned short* OA = (unsigned short*)(recA + 64);
        for (int qg = 0; qg < 4; ++qg)
            for (int j = 0; j < 2; ++j)
                for (int r = 0; r < 4; ++r)
                    OA[(qg * 16 + gq * 4 + r) * 128 + (w * 2 + j) * 16 + i16] = f2bf(acc[0][qg][j][r]);
    }
    {
        if (gq == 0) recB[w * 16 + i16] = lsumB;
        unsigned short* OB = (unsigned short*)(recB + 64);
        for (int qg = 0; qg < 4; ++qg)
            for (int j = 0; j < 2; ++j)
                for (int r = 0; r < 4; ++r)
                    OB[(qg * 16 + gq * 4 + r) * 128 + (w * 2 + j) * 16 + i16] = f2bf(acc[1][qg][j][r]);
    }
}

// ---------------- combine: sum valid chunks per branch, normalize, o1 - lam*o2 ----------
__global__ __launch_bounds__(256) void diff_combine(
    const float* __restrict__ part,
    const float* __restrict__ lq1, const float* __restrict__ lq2,
    const float* __restrict__ lk1, const float* __restrict__ lk2,
    float* __restrict__ out, int ncs) {
    const int t = blockIdx.x, b = blockIdx.y;
    const int tid = threadIdx.x;
    const int nc = 1 << ncs;
    const int n = (t | 1) + 1;  // pair length for row t's block
    __shared__ float sl[2][64];
    __shared__ float s_lam;

    const float* recbase = part + (((size_t)(b * 64 + t) << ncs)) * 2 * REC_FLOATS;

    if (tid < 64) {
        float s1 = lq1[tid] * lk1[tid];
        float s2 = lq2[tid] * lk2[tid];
        for (int off = 32; off > 0; off >>= 1) {
            s1 += __shfl_xor(s1, off);
            s2 += __shfl_xor(s2, off);
        }
        if (tid == 0) s_lam = expf(s1) - expf(s2) + LAMBDA_INIT;
    }
    if (tid < 128) {
        int r = tid & 63, br = tid >> 6;
        float acc = 0.f;
        for (int c = 0; c < nc; ++c) {
            int lo = (c * n) >> ncs, hi = ((c + 1) * n) >> ncs;
            if (lo >= hi || lo > t) continue;  // chunk not written for this row
            acc += recbase[(c * 2 + br) * REC_FLOATS + r];
        }
        sl[br][r] = acc;
    }
    __syncthreads();
    const float lam = s_lam;

    float* op = out + ((size_t)b * 4096 + (size_t)t * 64) * 128;
    for (int grp = 0; grp < 4; ++grp) {
        int gid = grp * 256 + tid;
        int e = gid * 8;
        int row = e >> 7;
        float o1[8] = {0, 0, 0, 0, 0, 0, 0, 0}, o2[8] = {0, 0, 0, 0, 0, 0, 0, 0};
        for (int c = 0; c < nc; ++c) {
            int lo = (c * n) >> ncs, hi = ((c + 1) * n) >> ncs;
            if (lo >= hi || lo > t) continue;
            const unsigned short* O0 = (const unsigned short*)(recbase + (c * 2 + 0) * REC_FLOATS + 64);
            const unsigned short* O1 = (const unsigned short*)(recbase + (c * 2 + 1) * REC_FLOATS + 64);
            uint4 u0 = *(const uint4*)&O0[e];
            uint4 u1 = *(const uint4*)&O1[e];
            const unsigned short* e0 = (const unsigned short*)&u0;
            const unsigned short* e1 = (const unsigned short*)&u1;
            #pragma unroll
            for (int j = 0; j < 8; ++j) {
                o1[j] += bf2f(e0[j]);
                o2[j] += bf2f(e1[j]);
            }
        }
        float l1inv = 1.0f / sl[0][row], l2inv = 1.0f / sl[1][row];
        float res[8];
        #pragma unroll
        for (int j = 0; j < 8; ++j) res[j] = o1[j] * l1inv - lam * o2[j] * l2inv;
        *(float4*)&op[e] = *(float4*)&res[0];
        *(float4*)&op[e + 4] = *(float4*)&res[4];
    }
}

extern "C" void kernel_launch(void* const* d_in, const int* in_sizes, int n_in,
                              void* d_out, int out_size, void* d_ws, size_t ws_size,
                              hipStream_t stream) {
    const float* x   = (const float*)d_in[0];
    const float* Wq  = (const float*)d_in[1];
    const float* Wk  = (const float*)d_in[2];
    const float* Wv  = (const float*)d_in[3];
    const float* lq1 = (const float*)d_in[4];
    const float* lq2 = (const float*)d_in[5];
    const float* lk1 = (const float*)d_in[6];
    const float* lk2 = (const float*)d_in[7];
    float* out = (float*)d_out;
    unsigned short* qkv = (unsigned short*)d_ws;

    const int ncs = 2;  // 4 kv-chunks (round-13-proven best total)
    const size_t part_bytes = (size_t)256 * (1 << ncs) * 2 * REC_FLOATS * 4;
    float* part = (float*)((char*)d_ws + PART_OFF_BYTES);
    unsigned short* WT = (unsigned short*)((char*)d_ws + PART_OFF_BYTES + part_bytes);

    prep_wt<<<dim3(16, 2, 3), 256, 0, stream>>>(Wq, Wk, Wv, WT);
    qkv_gemm<<<dim3(256, 3), 256, 0, stream>>>(x, WT, qkv);

    const unsigned short* qb = qkv;
    const unsigned short* kb = qkv + K_OFF;
    const unsigned short* vtb = qkv + VT_OFF;
    diff_attn_pair<<<dim3(32, 4, 2 << ncs), 256, 0, stream>>>(qb, kb, vtb, part, ncs);
    diff_combine<<<dim3(64, 4), 256, 0, stream>>>(part, lq1, lq2, lk1, lk2, out, ncs);
}

// Round 16
// 96.176 us; speedup vs baseline: 1.2415x; 1.2415x over previous
//
#include <hip/hip_runtime.h>
#include <hip/hip_bf16.h>

typedef __bf16 bf16x8 __attribute__((ext_vector_type(8)));
typedef float f32x4 __attribute__((ext_vector_type(4)));

#define LAMBDA_INIT 0.3555090675909693f
#define CEXP 0.18033688011112042f   // 0.125 * log2(e), folded into Q at projection

// ws layout (bytes):
//  q    : [0, 4.19M)       bf16 [16384][128] row-major, PRE-SCALED by CEXP
//  kimg : [4.19M, 8.39M)   bf16 [4][64][2][8 regions][64 slots][8]  (frag image)
//  vimg : [8.39M, 12.58M)  bf16 [4][64][16 regions][64 slots][8]    (frag image)
//  part : [12.58M, +34.1M) recs x 16640B (l[64] f32 + O[64][128] bf16)
//  WT   : after part       bf16 [3][128][1024]
#define K_OFF   ((size_t)16384 * 128)
#define VT_OFF  ((size_t)2 * 16384 * 128)
#define PART_OFF_BYTES ((size_t)12582912)
#define REC_FLOATS 4160  // 64 l + 4096 words of bf16 O

__device__ __forceinline__ unsigned short f2bf(float f) {
    __hip_bfloat16 h = __float2bfloat16(f);
    unsigned short u;
    __builtin_memcpy(&u, &h, 2);
    return u;
}
__device__ __forceinline__ float bf2f(unsigned short u) {
    unsigned int x = ((unsigned int)u) << 16;
    float f;
    __builtin_memcpy(&f, &x, 4);
    return f;
}
__device__ __forceinline__ unsigned int cvt_pk_bf16(float a, float b) {
    unsigned int r;
    asm volatile("v_cvt_pk_bf16_f32 %0, %1, %2" : "=v"(r) : "v"(a), "v"(b));
    return r;
}

// ---------------- W pre-transpose: [1024][128] f32 -> [128][1024] bf16 ----------------
__global__ __launch_bounds__(256) void prep_wt(
    const float* __restrict__ Wq, const float* __restrict__ Wk,
    const float* __restrict__ Wv, unsigned short* __restrict__ WT) {
    const int kt = blockIdx.x, nt = blockIdx.y, mat = blockIdx.z;
    const float* W = (mat == 0) ? Wq : (mat == 1) ? Wk : Wv;
    unsigned short* O = WT + (size_t)mat * 128 * 1024;
    __shared__ float tb[64][65];
    const int r = threadIdx.x >> 2, c4 = (threadIdx.x & 3) * 16;
    for (int j = 0; j < 4; ++j) {
        float4 v = *(const float4*)&W[(size_t)(kt * 64 + r) * 128 + nt * 64 + c4 + j * 4];
        tb[r][c4 + j * 4 + 0] = v.x;
        tb[r][c4 + j * 4 + 1] = v.y;
        tb[r][c4 + j * 4 + 2] = v.z;
        tb[r][c4 + j * 4 + 3] = v.w;
    }
    __syncthreads();
    unsigned short tmp[16];
    for (int j = 0; j < 16; ++j) tmp[j] = f2bf(tb[c4 + j][r]);
    *(uint4*)&O[(size_t)(nt * 64 + r) * 1024 + kt * 64 + c4] = *(uint4*)&tmp[0];
    *(uint4*)&O[(size_t)(nt * 64 + r) * 1024 + kt * 64 + c4 + 8] = *(uint4*)&tmp[8];
}

// ---------------- QKV projection, 64-row tiles, reg-prefetched staging ----------------
// grid (256, 3): 768 blocks = exactly 3/CU, co-resident, zero makespan skew.
// id = rx + 256*mat: same row-tile across mats on SAME XCD (256%8==0) -> x L2/L3 hits.
// T14: next k-step's x (4x float4) + W^T (4x uint4) loads issued into NAMED
// registers right after the current tile's LDS store -> 8 loads in flight
// across the MFMA phase (R15's 48-VGPR build serialized them: 64us).
// Q epilogue pre-scales by CEXP; K/V epilogues write the attention frag images.
__global__ __launch_bounds__(256) void qkv_gemm(
    const float* __restrict__ x, const unsigned short* __restrict__ WT,
    unsigned short* __restrict__ qkv) {
    const int tid = threadIdx.x;
    const int l = tid & 63, w = tid >> 6;
    const int g = l >> 4, i16 = l & 15;
    const int row0 = blockIdx.x * 64;
    const int mat = blockIdx.y;
    const unsigned short* Wt = WT + (size_t)mat * 128 * 1024;

    __shared__ unsigned short xs[64][72];
    __shared__ unsigned short wt[128][72];

    f32x4 acc[8];
    const f32x4 z4 = {0.f, 0.f, 0.f, 0.f};
    for (int nb = 0; nb < 8; ++nb) acc[nb] = z4;

    // staging geometry: x 4x float4/thread, W 4x uint4/thread
    const int xr = tid >> 4;             // + it*16
    const int xc = (tid & 15) * 4;
    const int wn = tid >> 3;             // + it*32
    const int wk8 = (tid & 7) * 8;
    const float* xp0 = &x[(size_t)(row0 + xr) * 1024 + xc];
    const unsigned short* wp0 = &Wt[(size_t)wn * 1024 + wk8];

    float4 fx0, fx1, fx2, fx3;
    uint4 fw0, fw1, fw2, fw3;

#define QKV_ISSUE(k0_) do {                                                 \
        fx0 = *(const float4*)&xp0[(k0_)];                                  \
        fx1 = *(const float4*)&xp0[16 * 1024 + (k0_)];                      \
        fx2 = *(const float4*)&xp0[32 * 1024 + (k0_)];                      \
        fx3 = *(const float4*)&xp0[48 * 1024 + (k0_)];                      \
        fw0 = *(const uint4*)&wp0[(k0_)];                                   \
        fw1 = *(const uint4*)&wp0[32 * 1024 + (k0_)];                       \
        fw2 = *(const uint4*)&wp0[64 * 1024 + (k0_)];                       \
        fw3 = *(const uint4*)&wp0[96 * 1024 + (k0_)];                       \
    } while (0)

#define QKV_STORE() do {                                                    \
        *(ushort4*)&xs[xr +  0][xc] = make_ushort4(f2bf(fx0.x), f2bf(fx0.y), f2bf(fx0.z), f2bf(fx0.w)); \
        *(ushort4*)&xs[xr + 16][xc] = make_ushort4(f2bf(fx1.x), f2bf(fx1.y), f2bf(fx1.z), f2bf(fx1.w)); \
        *(ushort4*)&xs[xr + 32][xc] = make_ushort4(f2bf(fx2.x), f2bf(fx2.y), f2bf(fx2.z), f2bf(fx2.w)); \
        *(ushort4*)&xs[xr + 48][xc] = make_ushort4(f2bf(fx3.x), f2bf(fx3.y), f2bf(fx3.z), f2bf(fx3.w)); \
        *(uint4*)&wt[wn +  0][wk8] = fw0;                                   \
        *(uint4*)&wt[wn + 32][wk8] = fw1;                                   \
        *(uint4*)&wt[wn + 64][wk8] = fw2;                                   \
        *(uint4*)&wt[wn + 96][wk8] = fw3;                                   \
    } while (0)

    QKV_ISSUE(0);
    #pragma unroll 1
    for (int k0 = 0; k0 < 1024; k0 += 64) {
        __syncthreads();       // prev MFMA done reading LDS
        QKV_STORE();
        if (k0 + 64 < 1024) QKV_ISSUE(k0 + 64);
        __syncthreads();       // LDS ready

        bf16x8 af0 = *(const bf16x8*)&xs[w * 16 + i16][8 * g];
        bf16x8 af1 = *(const bf16x8*)&xs[w * 16 + i16][32 + 8 * g];
        #pragma unroll
        for (int nb = 0; nb < 8; ++nb) {
            bf16x8 b0 = *(const bf16x8*)&wt[nb * 16 + i16][8 * g];
            bf16x8 b1 = *(const bf16x8*)&wt[nb * 16 + i16][32 + 8 * g];
            acc[nb] = __builtin_amdgcn_mfma_f32_16x16x32_bf16(af0, b0, acc[nb], 0, 0, 0);
            acc[nb] = __builtin_amdgcn_mfma_f32_16x16x32_bf16(af1, b1, acc[nb], 0, 0, 0);
        }
    }
#undef QKV_ISSUE
#undef QKV_STORE

    // epilogue: bounce through LDS (alias over wt), then frag-image writes
    __syncthreads();
    unsigned short(*ts)[136] = (unsigned short(*)[136]) & wt[0][0];
    const float qscale = (mat == 0) ? CEXP : 1.0f;
    for (int nb = 0; nb < 8; ++nb)
        for (int r = 0; r < 4; ++r)
            ts[w * 16 + g * 4 + r][nb * 16 + i16] = f2bf(acc[nb][r] * qscale);
    __syncthreads();

    const int bq = row0 >> 12;           // batch
    const int s = (row0 >> 6) & 63;      // kv-tile index
    if (mat == 0) {
        unsigned short* outp = qkv + (size_t)row0 * 128;
        #pragma unroll
        for (int it = 0; it < 4; ++it) {
            int tr = it * 16 + (tid >> 4), dv0 = (tid & 15) * 8;
            *(uint4*)&outp[tr * 128 + dv0] = *(const uint4*)&ts[tr][dv0];
        }
    } else if (mat == 1) {
        // K frag image: [(b*64+s)*2+branch][region=cb*2+cc][slot=gq*16+i16][8]
        unsigned short* kimg = qkv + K_OFF + ((size_t)(bq * 64 + s) * 2) * 4096;
        #pragma unroll
        for (int it = 0; it < 4; ++it) {
            int lin = it * 256 + tid;      // 0..1023
            int branch_ = (lin >> 9) & 1;
            int region = (lin >> 6) & 7;
            int slot = lin & 63;
            int row = (region >> 1) * 16 + (slot & 15);
            int d = branch_ * 64 + (region & 1) * 32 + (slot >> 4) * 8;
            uint4 vv = *(const uint4*)&ts[row][d];
            *(uint4*)&kimg[(size_t)branch_ * 4096 + (region * 64 + slot) * 8] = vv;
        }
    } else {
        // V frag image: [b*64+s][region=nb*2+cc][slot=gq*16+i16][8]
        unsigned short* vimg = qkv + VT_OFF + (size_t)(bq * 64 + s) * 8192;
        #pragma unroll
        for (int it = 0; it < 4; ++it) {
            int lin = it * 256 + tid;      // 0..1023
            int region = lin >> 6;         // 0..15
            int slot = lin & 63;
            int dv = (region >> 1) * 16 + (slot & 15);
            int kv0 = (region & 1) * 32 + (slot >> 4) * 8;
            unsigned short tmp[8];
            #pragma unroll
            for (int e = 0; e < 8; ++e) tmp[e] = ts[kv0 + e][dv];
            *(uint4*)&vimg[(region * 64 + slot) * 8] = *(uint4*)tmp;
        }
    }
}

// ---------------- Differential causal flash attention, paired rows ----------------
// grid (32, 4, nc*2): z = c*2+branch, nc = 4. Block owns adjacent row PAIR
// (t_e = 62-2bxe, t_o = 63-2bxe); every staged kv-tile serves two 64-row
// q-tiles. COMPLEMENT SWIZZLE: bxe = (c&1)?31-bx:bx -> same-CU blocks get
// complementary durations -> every CU gets equal tile totals.
// Q pre-scaled by CEXP and fixed-max offset folded out: p = exp2(S').
// Wave w: q-rows [w*16,w*16+16) of BOTH rows for QK/softmax; PV computes ALL
// q x dv-slice [32w,32w+32) with V in REGISTERS (direct frag-image loads).
// P via 16KB psf (cross-wave -> barrier before PV). LDS = 24KB.
// Empty chunks return WITHOUT writing; combine skips them.
__global__ __launch_bounds__(256, 3) void diff_attn_pair(
    const unsigned short* __restrict__ q, const unsigned short* __restrict__ kimg,
    const unsigned short* __restrict__ vimg,
    float* __restrict__ part, int ncs) {
    const int bx = blockIdx.x, b = blockIdx.y;
    const int c = blockIdx.z >> 1, branch = blockIdx.z & 1;
    const int bxe = (c & 1) ? (31 - bx) : bx;   // complement swizzle (load balance)
    const int t_o = 63 - 2 * bxe, t_e = t_o - 1;
    const int n = t_o + 1;
    const int s_lo = (c * n) >> ncs, smax = ((c + 1) * n) >> ncs;

    if (s_lo >= smax) return;  // empty chunk: no record (combine skips)

    const int tid = threadIdx.x;
    const int l = tid & 63, w = tid >> 6;
    const int gq = l >> 4, i16 = l & 15;
    const float NEGINF = -__builtin_inff();

    __shared__ unsigned short ksf[4096];  //  8 KB: [8 region][64 slot][8]
    __shared__ unsigned short psf[8192];  // 16 KB: [2 qset][4 qg][2 cc][64 slot][8]

    float* recA = part + ((((size_t)(b * 64 + t_e) << ncs) + c) * 2 + branch) * REC_FLOATS;
    float* recB = part + ((((size_t)(b * 64 + t_o) << ncs) + c) * 2 + branch) * REC_FLOATS;
    const bool emptyA = (s_lo > t_e);  // chunk == {t_o}: no A record

    const size_t bbase = (size_t)b * 4096;
    const unsigned short* kimg_b = kimg + (size_t)b * 524288;
    const unsigned short* vimg_b = vimg + (size_t)b * 524288;
    const int tid8 = tid * 8;
    const int l8 = l * 8;
    const f32x4 z4 = {0.f, 0.f, 0.f, 0.f};

    bf16x8 qfA[2], qfB[2];
    #pragma unroll
    for (int cc = 0; cc < 2; ++cc) {
        qfA[cc] = *(const bf16x8*)&q[(bbase + t_e * 64 + w * 16 + i16) * 128 + branch * 64 + cc * 32 + 8 * gq];
        qfB[cc] = *(const bf16x8*)&q[(bbase + t_o * 64 + w * 16 + i16) * 128 + branch * 64 + cc * 32 + 8 * gq];
    }

    float lsumA = 0.f, lsumB = 0.f;
    f32x4 acc[2][4][2];  // [qset][qg][j]  (dv slice w*32 + j*16)
    for (int qs = 0; qs < 2; ++qs)
        for (int qg = 0; qg < 4; ++qg)
            for (int j = 0; j < 2; ++j) acc[qs][qg][j] = z4;

    // P write slots (per cb, shared formula for both qsets; +qset*8 regions)
    int pdst[4];
    #pragma unroll
    for (int cb = 0; cb < 4; ++cb)
        pdst[cb] = ((w * 2 + (cb >> 1)) * 64 + ((cb & 1) * 2 + (gq >> 1)) * 16 + i16) * 8 + (gq & 1) * 4;

    uint4 kr0, kr1;
    bf16x8 vb00, vb01, vb10, vb11;  // V dv-slice frags, [j][cc]

#define K_ISSUE(s_) do {                                                            \
        const unsigned short* kp = &kimg_b[((size_t)(s_) * 2 + branch) * 4096];     \
        kr0 = *(const uint4*)&kp[tid8];                                             \
        kr1 = *(const uint4*)&kp[tid8 + 2048];                                      \
    } while (0)
#define V_ISSUE(s_) do {                                                            \
        const unsigned short* vp = &vimg_b[(size_t)(s_) * 8192 + w * 2048];         \
        vb00 = *(const bf16x8*)&vp[l8];                                             \
        vb01 = *(const bf16x8*)&vp[512 + l8];                                       \
        vb10 = *(const bf16x8*)&vp[1024 + l8];                                      \
        vb11 = *(const bf16x8*)&vp[1536 + l8];                                      \
    } while (0)

    K_ISSUE(s_lo);
    V_ISSUE(s_lo);
    #pragma unroll 1
    for (int s = s_lo; s < smax; ++s) {
        __syncthreads();                              // B1: prev PV done with ksf/psf
        *(uint4*)&ksf[tid8] = kr0;
        *(uint4*)&ksf[tid8 + 2048] = kr1;
        if (s + 1 < smax) K_ISSUE(s + 1);
        __syncthreads();                              // B2: ksf ready
        const bool aAct = (s != t_o);

        // ---- qset A (row t_e) ----
        if (aAct) {
            f32x4 sc[4];
            for (int cb = 0; cb < 4; ++cb) sc[cb] = z4;
            __builtin_amdgcn_s_setprio(1);
            #pragma unroll
            for (int cb = 0; cb < 4; ++cb)
                for (int cc = 0; cc < 2; ++cc) {
                    bf16x8 kf = *(const bf16x8*)&ksf[((cb * 2 + cc) * 64 + l) * 8];
                    sc[cb] = __builtin_amdgcn_mfma_f32_16x16x32_bf16(kf, qfA[cc], sc[cb], 0, 0, 0);
                }
            __builtin_amdgcn_s_setprio(0);
            if (s == t_e) {
                int ql = w * 16 + i16;
                for (int cb = 0; cb < 4; ++cb)
                    for (int r = 0; r < 4; ++r)
                        if (cb * 16 + gq * 4 + r > ql) sc[cb][r] = NEGINF;
            }
            #pragma unroll
            for (int cb = 0; cb < 4; ++cb) {
                float p0 = exp2f(sc[cb][0]);
                float p1 = exp2f(sc[cb][1]);
                float p2 = exp2f(sc[cb][2]);
                float p3 = exp2f(sc[cb][3]);
                lsumA += (p0 + p1) + (p2 + p3);
                uint2 pw;
                pw.x = cvt_pk_bf16(p0, p1);
                pw.y = cvt_pk_bf16(p2, p3);
                *(uint2*)&psf[pdst[cb]] = pw;
            }
        }
        // ---- qset B (row t_o) ----
        {
            f32x4 sc[4];
            for (int cb = 0; cb < 4; ++cb) sc[cb] = z4;
            __builtin_amdgcn_s_setprio(1);
            #pragma unroll
            for (int cb = 0; cb < 4; ++cb)
                for (int cc = 0; cc < 2; ++cc) {
                    bf16x8 kf = *(const bf16x8*)&ksf[((cb * 2 + cc) * 64 + l) * 8];
                    sc[cb] = __builtin_amdgcn_mfma_f32_16x16x32_bf16(kf, qfB[cc], sc[cb], 0, 0, 0);
                }
            __builtin_amdgcn_s_setprio(0);
            if (s == t_o) {
                int ql = w * 16 + i16;
                for (int cb = 0; cb < 4; ++cb)
                    for (int r = 0; r < 4; ++r)
                        if (cb * 16 + gq * 4 + r > ql) sc[cb][r] = NEGINF;
            }
            #pragma unroll
            for (int cb = 0; cb < 4; ++cb) {
                float p0 = exp2f(sc[cb][0]);
                float p1 = exp2f(sc[cb][1]);
                float p2 = exp2f(sc[cb][2]);
                float p3 = exp2f(sc[cb][3]);
                lsumB += (p0 + p1) + (p2 + p3);
                uint2 pw;
                pw.x = cvt_pk_bf16(p0, p1);
                pw.y = cvt_pk_bf16(p2, p3);
                *(uint2*)&psf[4096 + pdst[cb]] = pw;
            }
        }
        __syncthreads();                              // B3: psf complete (cross-wave)

        // ---- PV: all q x dv-slice [w*32, w*32+32), V in registers ----
        __builtin_amdgcn_s_setprio(1);
        if (aAct) {
            #pragma unroll
            for (int qg = 0; qg < 4; ++qg) {
                bf16x8 pa0 = *(const bf16x8*)&psf[(qg * 2 + 0) * 512 + l8];
                bf16x8 pa1 = *(const bf16x8*)&psf[(qg * 2 + 1) * 512 + l8];
                acc[0][qg][0] = __builtin_amdgcn_mfma_f32_16x16x32_bf16(pa0, vb00, acc[0][qg][0], 0, 0, 0);
                acc[0][qg][0] = __builtin_amdgcn_mfma_f32_16x16x32_bf16(pa1, vb01, acc[0][qg][0], 0, 0, 0);
                acc[0][qg][1] = __builtin_amdgcn_mfma_f32_16x16x32_bf16(pa0, vb10, acc[0][qg][1], 0, 0, 0);
                acc[0][qg][1] = __builtin_amdgcn_mfma_f32_16x16x32_bf16(pa1, vb11, acc[0][qg][1], 0, 0, 0);
            }
        }
        #pragma unroll
        for (int qg = 0; qg < 4; ++qg) {
            bf16x8 pa0 = *(const bf16x8*)&psf[4096 + (qg * 2 + 0) * 512 + l8];
            bf16x8 pa1 = *(const bf16x8*)&psf[4096 + (qg * 2 + 1) * 512 + l8];
            acc[1][qg][0] = __builtin_amdgcn_mfma_f32_16x16x32_bf16(pa0, vb00, acc[1][qg][0], 0, 0, 0);
            acc[1][qg][0] = __builtin_amdgcn_mfma_f32_16x16x32_bf16(pa1, vb01, acc[1][qg][0], 0, 0, 0);
            acc[1][qg][1] = __builtin_amdgcn_mfma_f32_16x16x32_bf16(pa0, vb10, acc[1][qg][1], 0, 0, 0);
            acc[1][qg][1] = __builtin_amdgcn_mfma_f32_16x16x32_bf16(pa1, vb11, acc[1][qg][1], 0, 0, 0);
        }
        __builtin_amdgcn_s_setprio(0);
        if (s + 1 < smax) V_ISSUE(s + 1);             // fly through next QK/softmax
    }
#undef K_ISSUE
#undef V_ISSUE

    // flush: lsum reduce across gq groups; O slices to both records
    lsumA += __shfl_xor(lsumA, 16);
    lsumA += __shfl_xor(lsumA, 32);
    lsumB += __shfl_xor(lsumB, 16);
    lsumB += __shfl_xor(lsumB, 32);
    if (!emptyA) {
        if (gq == 0) recA[w * 16 + i16] = lsumA;
        unsigned short* OA = (unsigned short*)(recA + 64);
        for (int qg = 0; qg < 4; ++qg)
            for (int j = 0; j < 2; ++j)
                for (int r = 0; r < 4; ++r)
                    OA[(qg * 16 + gq * 4 + r) * 128 + (w * 2 + j) * 16 + i16] = f2bf(acc[0][qg][j][r]);
    }
    {
        if (gq == 0) recB[w * 16 + i16] = lsumB;
        unsigned short* OB = (unsigned short*)(recB + 64);
        for (int qg = 0; qg < 4; ++qg)
            for (int j = 0; j < 2; ++j)
                for (int r = 0; r < 4; ++r)
                    OB[(qg * 16 + gq * 4 + r) * 128 + (w * 2 + j) * 16 + i16] = f2bf(acc[1][qg][j][r]);
    }
}

// ---------------- combine: sum valid chunks per branch, normalize, o1 - lam*o2 ----------
__global__ __launch_bounds__(256) void diff_combine(
    const float* __restrict__ part,
    const float* __restrict__ lq1, const float* __restrict__ lq2,
    const float* __restrict__ lk1, const float* __restrict__ lk2,
    float* __restrict__ out, int ncs) {
    const int t = blockIdx.x, b = blockIdx.y;
    const int tid = threadIdx.x;
    const int nc = 1 << ncs;
    const int n = (t | 1) + 1;  // pair length for row t's block
    __shared__ float sl[2][64];
    __shared__ float s_lam;

    const float* recbase = part + (((size_t)(b * 64 + t) << ncs)) * 2 * REC_FLOATS;

    if (tid < 64) {
        float s1 = lq1[tid] * lk1[tid];
        float s2 = lq2[tid] * lk2[tid];
        for (int off = 32; off > 0; off >>= 1) {
            s1 += __shfl_xor(s1, off);
            s2 += __shfl_xor(s2, off);
        }
        if (tid == 0) s_lam = expf(s1) - expf(s2) + LAMBDA_INIT;
    }
    if (tid < 128) {
        int r = tid & 63, br = tid >> 6;
        float acc = 0.f;
        for (int c = 0; c < nc; ++c) {
            int lo = (c * n) >> ncs, hi = ((c + 1) * n) >> ncs;
            if (lo >= hi || lo > t) continue;  // chunk not written for this row
            acc += recbase[(c * 2 + br) * REC_FLOATS + r];
        }
        sl[br][r] = acc;
    }
    __syncthreads();
    const float lam = s_lam;

    float* op = out + ((size_t)b * 4096 + (size_t)t * 64) * 128;
    for (int grp = 0; grp < 4; ++grp) {
        int gid = grp * 256 + tid;
        int e = gid * 8;
        int row = e >> 7;
        float o1[8] = {0, 0, 0, 0, 0, 0, 0, 0}, o2[8] = {0, 0, 0, 0, 0, 0, 0, 0};
        for (int c = 0; c < nc; ++c) {
            int lo = (c * n) >> ncs, hi = ((c + 1) * n) >> ncs;
            if (lo >= hi || lo > t) continue;
            const unsigned short* O0 = (const unsigned short*)(recbase + (c * 2 + 0) * REC_FLOATS + 64);
            const unsigned short* O1 = (const unsigned short*)(recbase + (c * 2 + 1) * REC_FLOATS + 64);
            uint4 u0 = *(const uint4*)&O0[e];
            uint4 u1 = *(const uint4*)&O1[e];
            const unsigned short* e0 = (const unsigned short*)&u0;
            const unsigned short* e1 = (const unsigned short*)&u1;
            #pragma unroll
            for (int j = 0; j < 8; ++j) {
                o1[j] += bf2f(e0[j]);
                o2[j] += bf2f(e1[j]);
            }
        }
        float l1inv = 1.0f / sl[0][row], l2inv = 1.0f / sl[1][row];
        float res[8];
        #pragma unroll
        for (int j = 0; j < 8; ++j) res[j] = o1[j] * l1inv - lam * o2[j] * l2inv;
        *(float4*)&op[e] = *(float4*)&res[0];
        *(float4*)&op[e + 4] = *(float4*)&res[4];
    }
}

extern "C" void kernel_launch(void* const* d_in, const int* in_sizes, int n_in,
                              void* d_out, int out_size, void* d_ws, size_t ws_size,
                              hipStream_t stream) {
    const float* x   = (const float*)d_in[0];
    const float* Wq  = (const float*)d_in[1];
    const float* Wk  = (const float*)d_in[2];
    const float* Wv  = (const float*)d_in[3];
    const float* lq1 = (const float*)d_in[4];
    const float* lq2 = (const float*)d_in[5];
    const float* lk1 = (const float*)d_in[6];
    const float* lk2 = (const float*)d_in[7];
    float* out = (float*)d_out;
    unsigned short* qkv = (unsigned short*)d_ws;

    const int ncs = 2;  // 4 kv-chunks
    const size_t part_bytes = (size_t)256 * (1 << ncs) * 2 * REC_FLOATS * 4;
    float* part = (float*)((char*)d_ws + PART_OFF_BYTES);
    unsigned short* WT = (unsigned short*)((char*)d_ws + PART_OFF_BYTES + part_bytes);

    prep_wt<<<dim3(16, 2, 3), 256, 0, stream>>>(Wq, Wk, Wv, WT);
    qkv_gemm<<<dim3(256, 3), 256, 0, stream>>>(x, WT, qkv);

    const unsigned short* qb = qkv;
    const unsigned short* kb = qkv + K_OFF;
    const unsigned short* vtb = qkv + VT_OFF;
    diff_attn_pair<<<dim3(32, 4, 2 << ncs), 256, 0, stream>>>(qb, kb, vtb, part, ncs);
    diff_combine<<<dim3(64, 4), 256, 0, stream>>>(part, lq1, lq2, lk1, lk2, out, ncs);
}